// Round 11
// baseline (38.285 us; speedup 1.0000x reference)
//
#include <hip/hip_runtime.h>
#include <math.h>

// Problem constants: B=4, H=W=64, M=8, K=64
#define HW  4096
#define KK  64
#define BLK 256          // 4 waves per workgroup
#define BPW 2            // blocks per wave (one per 32-lane group)

__device__ __forceinline__ unsigned umin32(unsigned a, unsigned b) { return a < b ? a : b; }

__device__ __forceinline__ float softplusf(float x) {
    return fmaxf(x, 0.0f) + log1pf(expf(-fabsf(x)));
}

// 16-lane-row min via 4 fused v_min_u32_dpp row_ror levels (r9-verified,
// absmax 0.0). Every lane of each 16-row ends with the row min.
__device__ __forceinline__ unsigned row16_min_u32(unsigned x) {
    asm("s_nop 1\n\t"
        "v_min_u32_dpp %0, %0, %0 row_ror:1 row_mask:0xf bank_mask:0xf\n\t"
        "s_nop 1\n\t"
        "v_min_u32_dpp %0, %0, %0 row_ror:2 row_mask:0xf bank_mask:0xf\n\t"
        "s_nop 1\n\t"
        "v_min_u32_dpp %0, %0, %0 row_ror:4 row_mask:0xf bank_mask:0xf\n\t"
        "s_nop 1\n\t"
        "v_min_u32_dpp %0, %0, %0 row_ror:8 row_mask:0xf bank_mask:0xf\n\t"
        "s_nop 1"
        : "+v"(x));
    return x;
}

// Wave = 2 groups x 32 lanes; group g owns block bid = wv*2+g.
// Lane q (0..31) owns prediction slots 2q,2q+1 (float2/float4 loads) and
// target cells q and q+32 (so the 64-bit group mask = two 32-bit ballot
// words with shifts only).
__global__ __launch_bounds__(BLK) void assign_loss_kernel(
    const float2* __restrict__ ps2,   // pred_scores  as float2
    const float4* __restrict__ po4,   // pred_offsets as float4
    const int*    __restrict__ tgt,   // [B,512,512]
    float* __restrict__ pobj, float* __restrict__ ploc, int* __restrict__ pnp)
{
    const int lane = threadIdx.x & 63;
    const int wib  = threadIdx.x >> 6;
    const int wv   = blockIdx.x * 4 + wib;     // wave id (8192 total)
    const int g    = lane >> 5;                // group (block within wave)
    const int q    = lane & 31;
    const int bid  = wv * BPW + g;             // 0..16383
    const int b    = bid >> 12;
    const int n    = bid & (HW - 1);
    const int h    = n >> 6, w = n & 63;

    // predictions (coalesced): slots 2q, 2q+1
    const float2 sc = ps2[bid * 32 + q];
    const float4 pa = po4[bid * 32 + q];
    const float p00 = pa.x, p01 = pa.y;        // slot 2q   offsets (y,x)
    const float p10 = pa.z, p11 = pa.w;        // slot 2q+1 offsets
    const float s0 = sc.x, s1 = sc.y;

    // target cells q and q+32: tile rows q>>3 and 4+(q>>3), col q&7
    const int rb = (b * 512 + h * 8 + (q >> 3)) * 512 + w * 8 + (q & 7);
    const int bb0 = tgt[rb] > 0;
    const int bb1 = tgt[rb + 4 * 512] > 0;
    int cnt = bb0 + bb1;                        // each cell counted once

    const unsigned long long B0 = __ballot(bb0);
    const unsigned long long B1 = __ballot(bb1);
    const int sh = g * 32;
    unsigned mlo = (unsigned)(B0 >> sh);        // group cells 0..31
    unsigned mhi = (unsigned)(B1 >> sh);        // group cells 32..63

    const float sig0 = 1.0f / (1.0f + expf(-s0));
    const float sig1 = 1.0f / (1.0f + expf(-s1));
    const float cl0  = sqrtf(sqrtf(1.0f - sig0));   // order-equiv ^0.25
    const float cl1  = sqrtf(sqrtf(1.0f - sig1));

    unsigned dead0 = 0u, dead1 = 0u;
    float locl0 = 0.0f, locl1 = 0.0f;

    // greedy: one cell per group per iteration, raster order
    while (__any((mlo | mhi) != 0u)) {
        const unsigned gd = ((mlo | mhi) == 0u) ? ~0u : 0u;   // group done
        const int t = (mlo != 0u) ? (__ffs(mlo) - 1) : (31 + __ffs(mhi));
        const unsigned nhi = (mlo == 0u) ? (mhi & (mhi - 1u)) : mhi;
        mlo &= (mlo - 1u);
        mhi = nhi;

        const float by = (float)(t >> 3) * 0.125f - 0.4375f;  // exact
        const float bx = (float)(t & 7)  * 0.125f - 0.4375f;  // exact

        const float l0 = fabsf(p00 - by) + fabsf(p01 - bx);
        const float l1 = fabsf(p10 - by) + fabsf(p11 - bx);
        // clean keys: cost bits (>=0 finite) | slot id; u32-min == cost
        // argmin with first-index tie-break (verified r2-r9, absmax 0.0)
        const unsigned k0 = (__float_as_uint(l0 * cl0) & ~63u) | (unsigned)(q * 2);
        const unsigned k1 = (__float_as_uint(l1 * cl1) & ~63u) | (unsigned)(q * 2 + 1);

        unsigned x = umin32(k0 | dead0, k1 | dead1) | gd;
        x = row16_min_u32(x);                       // row mins (4 DPP)
        // cross the two 16-rows within this 32-half (swizzle: xor-16)
        const unsigned y = (unsigned)__builtin_amdgcn_ds_swizzle((int)x, 0x401F);
        x = umin32(x, y);                           // all 32 lanes: group min

        const bool w0 = (k0 == x);                  // dead/done can't match
        const bool w1 = (k1 == x);
        dead0 = w0 ? ~0u : dead0;  locl0 = w0 ? l0 : locl0;
        dead1 = w1 ? ~0u : dead1;  locl1 = w1 ? l1 : locl1;
    }

    // losses
    float focal = 0.0f, locs = 0.0f;
    {
        const bool a0 = (dead0 != 0u);
        const float ce0  = a0 ? softplusf(-s0) : softplusf(s0);
        const float pt0  = a0 ? sig0 : (1.0f - sig0);
        const float om0  = 1.0f - pt0;
        focal += ce0 * om0 * om0 * (a0 ? 0.6f : 0.4f);
        locs  += locl0;
        const bool a1 = (dead1 != 0u);
        const float ce1  = a1 ? softplusf(-s1) : softplusf(s1);
        const float pt1  = a1 ? sig1 : (1.0f - sig1);
        const float om1  = 1.0f - pt1;
        focal += ce1 * om1 * om1 * (a1 ? 0.6f : 0.4f);
        locs  += locl1;
    }

    float fc = focal, lc = locs; int cc = cnt;
    #pragma unroll
    for (int o = 32; o; o >>= 1) {
        fc += __shfl_xor(fc, o, 64);
        lc += __shfl_xor(lc, o, 64);
        cc += __shfl_xor(cc, o, 64);
    }

    __shared__ float sobj[4], sloc[4];
    __shared__ int   snp[4];
    if (lane == 0) { sobj[wib] = fc; sloc[wib] = lc; snp[wib] = cc; }
    __syncthreads();
    if (threadIdx.x == 0) {
        float o = 0.0f, l = 0.0f; int np = 0;
        #pragma unroll
        for (int u = 0; u < 4; ++u) { o += sobj[u]; l += sloc[u]; np += snp[u]; }
        pobj[blockIdx.x] = o;
        ploc[blockIdx.x] = l;
        pnp [blockIdx.x] = np;
    }
}

__global__ __launch_bounds__(256) void finalize_kernel(
    const float* __restrict__ pobj,
    const float* __restrict__ ploc,
    const int*   __restrict__ pnp,
    int nb, float* __restrict__ out)
{
    __shared__ double so[256], sl[256];
    __shared__ long long sn[256];
    double o = 0.0, l = 0.0;
    long long np = 0;
    for (int i = threadIdx.x; i < nb; i += 256) {
        o  += (double)pobj[i];
        l  += (double)ploc[i];
        np += (long long)pnp[i];
    }
    so[threadIdx.x] = o; sl[threadIdx.x] = l; sn[threadIdx.x] = np;
    __syncthreads();
    for (int st = 128; st; st >>= 1) {
        if (threadIdx.x < st) {
            so[threadIdx.x] += so[threadIdx.x + st];
            sl[threadIdx.x] += sl[threadIdx.x + st];
            sn[threadIdx.x] += sn[threadIdx.x + st];
        }
        __syncthreads();
    }
    if (threadIdx.x == 0) {
        long long npos = sn[0] > 1 ? sn[0] : 1;
        out[0] = (float)((so[0] + 10.0 * sl[0]) / (double)npos);
    }
}

extern "C" void kernel_launch(void* const* d_in, const int* in_sizes, int n_in,
                              void* d_out, int out_size, void* d_ws, size_t ws_size,
                              hipStream_t stream) {
    const float2* ps2 = (const float2*)d_in[0];
    const float4* po4 = (const float4*)d_in[1];
    const int*    tgt = (const int*)d_in[2];

    const int total_blocks = in_sizes[0] / KK;     // 16384
    const int nwg = total_blocks / 8;              // 2048 (8 blocks per wg)

    float* pobj = (float*)d_ws;
    float* ploc = pobj + nwg;
    int*   pnp  = (int*)(ploc + nwg);

    assign_loss_kernel<<<nwg, BLK, 0, stream>>>(ps2, po4, tgt, pobj, ploc, pnp);
    finalize_kernel<<<1, 256, 0, stream>>>(pobj, ploc, pnp, nwg, (float*)d_out);
}